// Round 7
// baseline (698.755 us; speedup 1.0000x reference)
//
#include <hip/hip_runtime.h>

#define D_FEAT 64
constexpr float SLOPE = 0.01f;
constexpr float EPS_N = 1e-6f;
constexpr int SCAN_CHUNK = 2048;   // elements per scan block (256 thr x 8)
constexpr int LDT = 66;            // LDS row stride (pad 64 -> 66)
constexpr int CHUNK_E = 4096;      // edges per binning block
constexpr int BUCKET_SHIFT = 8;    // 256 nodes per bucket
constexpr int BUCKET_NODES = 256;
constexpr int NB_MAX = 512;        // max buckets supported by LDS hist

__device__ __forceinline__ float lrelu(float v) { return v >= 0.f ? v : SLOPE * v; }

// ---------------------------------------------------------------------------
// Stage 1: h = (leaky_relu(leaky_relu(x + states@Ws^T) @ W1^T)) @ W2^T
// Register-tiled f32 GEMM: block = 64-node tile, thread = 4 nodes x 4 ch.
// ---------------------------------------------------------------------------
__global__ __launch_bounds__(256, 3) void mlp_kernel(
    const float* __restrict__ x, const float* __restrict__ states,
    const float* __restrict__ Ws, const float* __restrict__ W1,
    const float* __restrict__ W2, float* __restrict__ h, int n_nodes)
{
    __shared__ float S_t[D_FEAT * LDT];
    __shared__ float H_t[D_FEAT * LDT];
    __shared__ float W_t[D_FEAT * LDT];

    const int t  = threadIdx.x;
    const int tn = t & 15;          // node group (4 nodes)
    const int tc = t >> 4;          // channel group (4 ch)
    const int nb = blockIdx.x * 64; // tile base node

#define STAGE_W(Wp)                                                          \
    {                                                                        \
        const int wrow = t >> 2;                                             \
        _Pragma("unroll")                                                    \
        for (int s = (t & 3); s < 16; s += 4) {                              \
            float4 wv = *reinterpret_cast<const float4*>((Wp) + wrow * 64 + s * 4); \
            W_t[(s * 4 + 0) * LDT + wrow] = wv.x;                            \
            W_t[(s * 4 + 1) * LDT + wrow] = wv.y;                            \
            W_t[(s * 4 + 2) * LDT + wrow] = wv.z;                            \
            W_t[(s * 4 + 3) * LDT + wrow] = wv.w;                            \
        }                                                                    \
    }

    STAGE_W(Ws);
    {
        const int r = t >> 4, kg = t & 15;
        #pragma unroll
        for (int i = 0; i < 4; ++i) {
            int nloc = r + i * 16;
            int node = nb + nloc;
            float4 sv = make_float4(0.f, 0.f, 0.f, 0.f);
            if (node < n_nodes)
                sv = *reinterpret_cast<const float4*>(states + (size_t)node * D_FEAT + kg * 4);
            S_t[(kg * 4 + 0) * LDT + nloc] = sv.x;
            S_t[(kg * 4 + 1) * LDT + nloc] = sv.y;
            S_t[(kg * 4 + 2) * LDT + nloc] = sv.z;
            S_t[(kg * 4 + 3) * LDT + nloc] = sv.w;
        }
    }
    __syncthreads();

    float acc[4][4];

    // ---- stage 1: h2 = lrelu(x + states @ Ws^T) ----
    #pragma unroll
    for (int i = 0; i < 4; ++i) {
        int node = nb + tn * 4 + i;
        if (node < n_nodes) {
            float4 xv = *reinterpret_cast<const float4*>(x + (size_t)node * D_FEAT + tc * 4);
            acc[i][0] = xv.x; acc[i][1] = xv.y; acc[i][2] = xv.z; acc[i][3] = xv.w;
        } else {
            acc[i][0] = acc[i][1] = acc[i][2] = acc[i][3] = 0.f;
        }
    }
    #pragma unroll 8
    for (int k = 0; k < D_FEAT; ++k) {
        float4 a = *reinterpret_cast<const float4*>(&S_t[k * LDT + tn * 4]);
        float4 b = *reinterpret_cast<const float4*>(&W_t[k * LDT + tc * 4]);
        const float av[4] = {a.x, a.y, a.z, a.w};
        const float bv[4] = {b.x, b.y, b.z, b.w};
        #pragma unroll
        for (int i = 0; i < 4; ++i)
            #pragma unroll
            for (int j = 0; j < 4; ++j)
                acc[i][j] += av[i] * bv[j];
    }
    #pragma unroll
    for (int i = 0; i < 4; ++i)
        #pragma unroll
        for (int j = 0; j < 4; ++j)
            H_t[(tc * 4 + j) * LDT + tn * 4 + i] = lrelu(acc[i][j]);
    __syncthreads();

    STAGE_W(W1);
    __syncthreads();

    // ---- stage 2: h3 = lrelu(h2 @ W1^T) ----
    #pragma unroll
    for (int i = 0; i < 4; ++i)
        #pragma unroll
        for (int j = 0; j < 4; ++j)
            acc[i][j] = 0.f;
    #pragma unroll 8
    for (int k = 0; k < D_FEAT; ++k) {
        float4 a = *reinterpret_cast<const float4*>(&H_t[k * LDT + tn * 4]);
        float4 b = *reinterpret_cast<const float4*>(&W_t[k * LDT + tc * 4]);
        const float av[4] = {a.x, a.y, a.z, a.w};
        const float bv[4] = {b.x, b.y, b.z, b.w};
        #pragma unroll
        for (int i = 0; i < 4; ++i)
            #pragma unroll
            for (int j = 0; j < 4; ++j)
                acc[i][j] += av[i] * bv[j];
    }
    #pragma unroll
    for (int i = 0; i < 4; ++i)
        #pragma unroll
        for (int j = 0; j < 4; ++j)
            S_t[(tc * 4 + j) * LDT + tn * 4 + i] = lrelu(acc[i][j]);
    __syncthreads();

    STAGE_W(W2);
    __syncthreads();

    // ---- stage 3: h = h3 @ W2^T ----
    #pragma unroll
    for (int i = 0; i < 4; ++i)
        #pragma unroll
        for (int j = 0; j < 4; ++j)
            acc[i][j] = 0.f;
    #pragma unroll 8
    for (int k = 0; k < D_FEAT; ++k) {
        float4 a = *reinterpret_cast<const float4*>(&S_t[k * LDT + tn * 4]);
        float4 b = *reinterpret_cast<const float4*>(&W_t[k * LDT + tc * 4]);
        const float av[4] = {a.x, a.y, a.z, a.w};
        const float bv[4] = {b.x, b.y, b.z, b.w};
        #pragma unroll
        for (int i = 0; i < 4; ++i)
            #pragma unroll
            for (int j = 0; j < 4; ++j)
                acc[i][j] += av[i] * bv[j];
    }
    #pragma unroll
    for (int i = 0; i < 4; ++i) {
        int node = nb + tn * 4 + i;
        if (node < n_nodes) {
            float4 o = make_float4(acc[i][0], acc[i][1], acc[i][2], acc[i][3]);
            *reinterpret_cast<float4*>(h + (size_t)node * D_FEAT + tc * 4) = o;
        }
    }
#undef STAGE_W
}

// ---------------------------------------------------------------------------
// Pass A: per-chunk bucket histogram (bucket = dst >> BUCKET_SHIFT).
// counts layout: bh[b * nch + c]  (bucket-major for the scan).
// ---------------------------------------------------------------------------
__global__ __launch_bounds__(256) void binhist_kernel(
    const int* __restrict__ eidx, int* __restrict__ bh,
    int n_edges, int nb, int nch)
{
    __shared__ int hist[NB_MAX];
    const int c = blockIdx.x, t = threadIdx.x;
    for (int i = t; i < nb; i += 256) hist[i] = 0;
    __syncthreads();
    const int base = c * CHUNK_E;
    #pragma unroll 4
    for (int k = 0; k < CHUNK_E / 256; ++k) {
        int e = base + k * 256 + t;
        if (e < n_edges) atomicAdd(&hist[eidx[e] >> BUCKET_SHIFT], 1);
    }
    __syncthreads();
    for (int i = t; i < nb; i += 256) bh[i * nch + c] = hist[i];
}

// ---------------------------------------------------------------------------
// Scan kernels (generic exclusive prefix over n ints)
// scan1: per-2048 chunk local exclusive (in-place safe: reads own elems first)
// ---------------------------------------------------------------------------
__global__ __launch_bounds__(256) void scan1_kernel(
    const int* __restrict__ in, int* __restrict__ out,
    int* __restrict__ partials, int n)
{
    __shared__ int s[256];
    const int b = blockIdx.x, t = threadIdx.x;
    const int base = b * SCAN_CHUNK + t * 8;
    int v[8]; int sum = 0;
    #pragma unroll
    for (int i = 0; i < 8; ++i) {
        v[i] = (base + i < n) ? in[base + i] : 0;
        sum += v[i];
    }
    s[t] = sum;
    __syncthreads();
    for (int off = 1; off < 256; off <<= 1) {
        int y = (t >= off) ? s[t - off] : 0;
        __syncthreads();
        s[t] += y;
        __syncthreads();
    }
    int excl = s[t] - sum;
    #pragma unroll
    for (int i = 0; i < 8; ++i) {
        if (base + i < n) out[base + i] = excl;
        excl += v[i];
    }
    if (t == 255) partials[b] = s[255];
}

__global__ __launch_bounds__(256) void scan2_kernel(int* partials, int nchunks)
{
    __shared__ int s[256];
    const int t = threadIdx.x;
    int v = (t < nchunks) ? partials[t] : 0;
    s[t] = v;
    __syncthreads();
    for (int off = 1; off < 256; off <<= 1) {
        int y = (t >= off) ? s[t - off] : 0;
        __syncthreads();
        s[t] += y;
        __syncthreads();
    }
    if (t < nchunks) partials[t] = s[t] - v;      // exclusive
}

__global__ __launch_bounds__(256) void scan3_kernel(
    int* __restrict__ data, const int* __restrict__ partials, int n)
{
    for (int i = blockIdx.x * blockDim.x + threadIdx.x; i < n;
         i += gridDim.x * blockDim.x)
        data[i] += partials[i / SCAN_CHUNK];
}

// ---------------------------------------------------------------------------
// Pass B: binned scatter. Each block ranks its chunk's edges per bucket via
// LDS cursors initialized from the scanned offsets -> records land in
// per-(bucket,chunk) contiguous runs (~10 recs avg => ~1.6x write amp).
// rec.x = (dstLocal << 20) | src  (src < 2^20), rec.y = w bits.
// ---------------------------------------------------------------------------
__global__ __launch_bounds__(256) void binscatter_kernel(
    const int* __restrict__ eidx, const float* __restrict__ w,
    const int* __restrict__ scanned, int2* __restrict__ rec,
    int n_edges, int nb, int nch)
{
    __shared__ int cur[NB_MAX];
    const int c = blockIdx.x, t = threadIdx.x;
    for (int i = t; i < nb; i += 256) cur[i] = scanned[i * nch + c];
    __syncthreads();
    const int base = c * CHUNK_E;
    #pragma unroll 4
    for (int k = 0; k < CHUNK_E / 256; ++k) {
        int e = base + k * 256 + t;
        if (e < n_edges) {
            int dst = eidx[e];
            int src = eidx[n_edges + e];
            float wv = w[e];
            int b = dst >> BUCKET_SHIFT;
            int dl = dst & (BUCKET_NODES - 1);
            int pos = atomicAdd(&cur[b], 1);
            rec[pos] = make_int2((dl << 20) | src, __float_as_int(wv));
        }
    }
}

// ---------------------------------------------------------------------------
// Pass C: per-bucket aggregation. Block b owns nodes [b*256, b*256+256);
// acc[256][64] f32 in LDS (exactly 64 KB). Stream the bucket's records:
// broadcast 8B rec load + coalesced 256B h-row load + ds_add_f32.
// Then write agg coalesced. Covers every node -> no memset needed.
// ---------------------------------------------------------------------------
__global__ __launch_bounds__(256) void binagg_kernel(
    const int* __restrict__ scanned, const int2* __restrict__ rec,
    const float* __restrict__ h, float* __restrict__ agg,
    int n_edges, int nb, int nch, int n_nodes)
{
    __shared__ float acc[BUCKET_NODES][D_FEAT];   // 64 KB
    const int b = blockIdx.x, t = threadIdx.x;
    const int lane = t & 63, wid = t >> 6;

    float* af = &acc[0][0];
    for (int i = t; i < BUCKET_NODES * D_FEAT; i += 256) af[i] = 0.f;
    __syncthreads();

    const int start = scanned[b * nch];
    const int end   = (b + 1 < nb) ? scanned[(b + 1) * nch] : n_edges;

    #pragma unroll 4
    for (int i = start + wid; i < end; i += 4) {
        int2 r = rec[i];
        int dl  = r.x >> 20;
        int src = r.x & 0xFFFFF;
        float wv = __int_as_float(r.y);
        float hv = h[(size_t)src * D_FEAT + lane];
        unsafeAtomicAdd(&acc[dl][lane], wv * hv);
    }
    __syncthreads();

    const int node0 = b << BUCKET_SHIFT;
    for (int r = wid; r < BUCKET_NODES; r += 4) {
        int node = node0 + r;
        if (node < n_nodes)
            agg[(size_t)node * D_FEAT + lane] = acc[r][lane];
    }
}

// ---------------------------------------------------------------------------
// Fallback scatter (atomics) if workspace too small / shape unsupported
// ---------------------------------------------------------------------------
__global__ __launch_bounds__(256) void scatter_atomic_kernel(
    const int* __restrict__ eidx, const float* __restrict__ w,
    const float* __restrict__ h, float* __restrict__ agg, int n_edges)
{
    long long t = (long long)blockIdx.x * blockDim.x + threadIdx.x;
    int e = (int)(t >> 4);
    if (e >= n_edges) return;
    int c = ((int)t & 15) * 4;
    int dst = eidx[e];
    int src = eidx[n_edges + e];
    float wv = w[e];
    const float4 hv = *reinterpret_cast<const float4*>(h + (size_t)src * D_FEAT + c);
    float* p = agg + (size_t)dst * D_FEAT + c;
    unsafeAtomicAdd(p + 0, wv * hv.x);
    unsafeAtomicAdd(p + 1, wv * hv.y);
    unsafeAtomicAdd(p + 2, wv * hv.z);
    unsafeAtomicAdd(p + 3, wv * hv.w);
}

// ---------------------------------------------------------------------------
// Stage 3: GraphNorm in place on d_out
// ---------------------------------------------------------------------------
__global__ __launch_bounds__(256) void norm_kernel(
    float* __restrict__ io, const float* __restrict__ gamma,
    const float* __restrict__ beta, int npg)
{
    const int g = blockIdx.x;
    const int t = threadIdx.x;
    const int j = t & 63;
    const int r = t >> 6;
    const size_t base = (size_t)g * npg * D_FEAT;

    float sum = 0.f, sq = 0.f;
    for (int n = r; n < npg; n += 4) {
        float v = io[base + (size_t)n * D_FEAT + j];
        sum += v; sq += v * v;
    }

    __shared__ float s_red[2][4][64];
    s_red[0][r][j] = sum;
    s_red[1][r][j] = sq;
    __syncthreads();

    __shared__ float s_mu[64], s_scale[64], s_beta[64];
    if (r == 0) {
        float S = s_red[0][0][j] + s_red[0][1][j] + s_red[0][2][j] + s_red[0][3][j];
        float Q = s_red[1][0][j] + s_red[1][1][j] + s_red[1][2][j] + s_red[1][3][j];
        float cnt = (float)npg;
        float mu = S / cnt;
        float var = (Q - cnt * mu * mu) / fmaxf(cnt - 1.f, 1.f);
        var = fmaxf(var, 0.f);
        s_mu[j]    = mu;
        s_scale[j] = gamma[j] / (sqrtf(var) + EPS_N);
        s_beta[j]  = beta[j];
    }
    __syncthreads();

    const float mu = s_mu[j], sc = s_scale[j], be = s_beta[j];
    for (int n = r; n < npg; n += 4) {
        size_t idx = base + (size_t)n * D_FEAT + j;
        io[idx] = (io[idx] - mu) * sc + be;
    }
}

extern "C" void kernel_launch(void* const* d_in, const int* in_sizes, int n_in,
                              void* d_out, int out_size, void* d_ws, size_t ws_size,
                              hipStream_t stream)
{
    const float* x      = (const float*)d_in[0];
    const float* states = (const float*)d_in[1];
    const int*   eidx   = (const int*)d_in[2];
    const float* w      = (const float*)d_in[3];
    const float* Ws     = (const float*)d_in[6];
    const float* W1     = (const float*)d_in[7];
    const float* W2     = (const float*)d_in[8];
    const float* gamma  = (const float*)d_in[9];
    const float* beta   = (const float*)d_in[10];

    const int n_nodes  = in_sizes[0] / D_FEAT;
    const int n_edges  = in_sizes[3];
    const int n_graphs = in_sizes[5];
    const int npg      = n_nodes / n_graphs;

    const int nb  = (n_nodes + BUCKET_NODES - 1) / BUCKET_NODES;  // 391
    const int nch = (n_edges + CHUNK_E - 1) / CHUNK_E;            // 293
    const int nscan = nb * nch;                                   // 114,563

    // workspace layout
    char* ws = (char*)d_ws;
    size_t hBytes   = (size_t)n_nodes * D_FEAT * sizeof(float);   // 25.6 MB
    size_t recBytes = (size_t)n_edges * sizeof(int2);             // 9.6 MB
    size_t bhBytes  = (size_t)nscan * sizeof(int);                // 458 KB
    size_t partBytes = 256 * sizeof(int);
    size_t need = hBytes + recBytes + bhBytes + partBytes;

    float* h   = (float*)ws;
    float* agg = (float*)d_out;

    mlp_kernel<<<(n_nodes + 63) / 64, 256, 0, stream>>>(x, states, Ws, W1, W2, h, n_nodes);

    const bool ok = (ws_size >= need) && (nb <= NB_MAX) && (n_nodes < (1 << 20));
    if (ok) {
        int2* rec      = (int2*)(ws + hBytes);
        int*  bh       = (int*)(ws + hBytes + recBytes);
        int*  partials = (int*)(ws + hBytes + recBytes + bhBytes);

        binhist_kernel<<<nch, 256, 0, stream>>>(eidx, bh, n_edges, nb, nch);

        int nchunks = (nscan + SCAN_CHUNK - 1) / SCAN_CHUNK;      // 56
        scan1_kernel<<<nchunks, 256, 0, stream>>>(bh, bh, partials, nscan);  // in-place
        scan2_kernel<<<1, 256, 0, stream>>>(partials, nchunks);
        scan3_kernel<<<256, 256, 0, stream>>>(bh, partials, nscan);

        binscatter_kernel<<<nch, 256, 0, stream>>>(eidx, w, bh, rec, n_edges, nb, nch);

        binagg_kernel<<<nb, 256, 0, stream>>>(bh, rec, h, agg, n_edges, nb, nch, n_nodes);
    } else {
        hipMemsetAsync(agg, 0, hBytes, stream);
        long long sthreads = (long long)n_edges * 16;
        int sblocks = (int)((sthreads + 255) / 256);
        scatter_atomic_kernel<<<sblocks, 256, 0, stream>>>(eidx, w, h, agg, n_edges);
    }

    norm_kernel<<<n_graphs, 256, 0, stream>>>(agg, gamma, beta, npg);
}

// Round 8
// 627.122 us; speedup vs baseline: 1.1142x; 1.1142x over previous
//
#include <hip/hip_runtime.h>

#define D_FEAT 64
constexpr float SLOPE = 0.01f;
constexpr float EPS_N = 1e-6f;
constexpr int SCAN_CHUNK = 2048;   // elements per scan block (256 thr x 8)
constexpr int LDT = 66;            // LDS row stride (pad 64 -> 66)
constexpr int CHUNK_E = 4096;      // edges per binning block
constexpr int BUCKET_SHIFT = 8;    // 256 nodes per bucket
constexpr int BUCKET_NODES = 256;
constexpr int NB_MAX = 512;        // max buckets supported by LDS hist
constexpr int NSPLIT = 8;          // blocks per graph for norm partial reduce

__device__ __forceinline__ float lrelu(float v) { return v >= 0.f ? v : SLOPE * v; }

// ---------------------------------------------------------------------------
// Stage 1: h = (leaky_relu(leaky_relu(x + states@Ws^T) @ W1^T)) @ W2^T
// Register-tiled f32 GEMM: block = 64-node tile, thread = 4 nodes x 4 ch.
// ---------------------------------------------------------------------------
__global__ __launch_bounds__(256, 3) void mlp_kernel(
    const float* __restrict__ x, const float* __restrict__ states,
    const float* __restrict__ Ws, const float* __restrict__ W1,
    const float* __restrict__ W2, float* __restrict__ h, int n_nodes)
{
    __shared__ float S_t[D_FEAT * LDT];
    __shared__ float H_t[D_FEAT * LDT];
    __shared__ float W_t[D_FEAT * LDT];

    const int t  = threadIdx.x;
    const int tn = t & 15;          // node group (4 nodes)
    const int tc = t >> 4;          // channel group (4 ch)
    const int nb = blockIdx.x * 64; // tile base node

#define STAGE_W(Wp)                                                          \
    {                                                                        \
        const int wrow = t >> 2;                                             \
        _Pragma("unroll")                                                    \
        for (int s = (t & 3); s < 16; s += 4) {                              \
            float4 wv = *reinterpret_cast<const float4*>((Wp) + wrow * 64 + s * 4); \
            W_t[(s * 4 + 0) * LDT + wrow] = wv.x;                            \
            W_t[(s * 4 + 1) * LDT + wrow] = wv.y;                            \
            W_t[(s * 4 + 2) * LDT + wrow] = wv.z;                            \
            W_t[(s * 4 + 3) * LDT + wrow] = wv.w;                            \
        }                                                                    \
    }

    STAGE_W(Ws);
    {
        const int r = t >> 4, kg = t & 15;
        #pragma unroll
        for (int i = 0; i < 4; ++i) {
            int nloc = r + i * 16;
            int node = nb + nloc;
            float4 sv = make_float4(0.f, 0.f, 0.f, 0.f);
            if (node < n_nodes)
                sv = *reinterpret_cast<const float4*>(states + (size_t)node * D_FEAT + kg * 4);
            S_t[(kg * 4 + 0) * LDT + nloc] = sv.x;
            S_t[(kg * 4 + 1) * LDT + nloc] = sv.y;
            S_t[(kg * 4 + 2) * LDT + nloc] = sv.z;
            S_t[(kg * 4 + 3) * LDT + nloc] = sv.w;
        }
    }
    __syncthreads();

    float acc[4][4];

    // ---- stage 1: h2 = lrelu(x + states @ Ws^T) ----
    #pragma unroll
    for (int i = 0; i < 4; ++i) {
        int node = nb + tn * 4 + i;
        if (node < n_nodes) {
            float4 xv = *reinterpret_cast<const float4*>(x + (size_t)node * D_FEAT + tc * 4);
            acc[i][0] = xv.x; acc[i][1] = xv.y; acc[i][2] = xv.z; acc[i][3] = xv.w;
        } else {
            acc[i][0] = acc[i][1] = acc[i][2] = acc[i][3] = 0.f;
        }
    }
    #pragma unroll 8
    for (int k = 0; k < D_FEAT; ++k) {
        float4 a = *reinterpret_cast<const float4*>(&S_t[k * LDT + tn * 4]);
        float4 b = *reinterpret_cast<const float4*>(&W_t[k * LDT + tc * 4]);
        const float av[4] = {a.x, a.y, a.z, a.w};
        const float bv[4] = {b.x, b.y, b.z, b.w};
        #pragma unroll
        for (int i = 0; i < 4; ++i)
            #pragma unroll
            for (int j = 0; j < 4; ++j)
                acc[i][j] += av[i] * bv[j];
    }
    #pragma unroll
    for (int i = 0; i < 4; ++i)
        #pragma unroll
        for (int j = 0; j < 4; ++j)
            H_t[(tc * 4 + j) * LDT + tn * 4 + i] = lrelu(acc[i][j]);
    __syncthreads();

    STAGE_W(W1);
    __syncthreads();

    // ---- stage 2: h3 = lrelu(h2 @ W1^T) ----
    #pragma unroll
    for (int i = 0; i < 4; ++i)
        #pragma unroll
        for (int j = 0; j < 4; ++j)
            acc[i][j] = 0.f;
    #pragma unroll 8
    for (int k = 0; k < D_FEAT; ++k) {
        float4 a = *reinterpret_cast<const float4*>(&H_t[k * LDT + tn * 4]);
        float4 b = *reinterpret_cast<const float4*>(&W_t[k * LDT + tc * 4]);
        const float av[4] = {a.x, a.y, a.z, a.w};
        const float bv[4] = {b.x, b.y, b.z, b.w};
        #pragma unroll
        for (int i = 0; i < 4; ++i)
            #pragma unroll
            for (int j = 0; j < 4; ++j)
                acc[i][j] += av[i] * bv[j];
    }
    #pragma unroll
    for (int i = 0; i < 4; ++i)
        #pragma unroll
        for (int j = 0; j < 4; ++j)
            S_t[(tc * 4 + j) * LDT + tn * 4 + i] = lrelu(acc[i][j]);
    __syncthreads();

    STAGE_W(W2);
    __syncthreads();

    // ---- stage 3: h = h3 @ W2^T ----
    #pragma unroll
    for (int i = 0; i < 4; ++i)
        #pragma unroll
        for (int j = 0; j < 4; ++j)
            acc[i][j] = 0.f;
    #pragma unroll 8
    for (int k = 0; k < D_FEAT; ++k) {
        float4 a = *reinterpret_cast<const float4*>(&S_t[k * LDT + tn * 4]);
        float4 b = *reinterpret_cast<const float4*>(&W_t[k * LDT + tc * 4]);
        const float av[4] = {a.x, a.y, a.z, a.w};
        const float bv[4] = {b.x, b.y, b.z, b.w};
        #pragma unroll
        for (int i = 0; i < 4; ++i)
            #pragma unroll
            for (int j = 0; j < 4; ++j)
                acc[i][j] += av[i] * bv[j];
    }
    #pragma unroll
    for (int i = 0; i < 4; ++i) {
        int node = nb + tn * 4 + i;
        if (node < n_nodes) {
            float4 o = make_float4(acc[i][0], acc[i][1], acc[i][2], acc[i][3]);
            *reinterpret_cast<float4*>(h + (size_t)node * D_FEAT + tc * 4) = o;
        }
    }
#undef STAGE_W
}

// ---------------------------------------------------------------------------
// Pass A: per-chunk bucket histogram (bucket = dst >> BUCKET_SHIFT).
// ---------------------------------------------------------------------------
__global__ __launch_bounds__(256) void binhist_kernel(
    const int* __restrict__ eidx, int* __restrict__ bh,
    int n_edges, int nb, int nch)
{
    __shared__ int hist[NB_MAX];
    const int c = blockIdx.x, t = threadIdx.x;
    for (int i = t; i < nb; i += 256) hist[i] = 0;
    __syncthreads();
    const int base = c * CHUNK_E;
    #pragma unroll 4
    for (int k = 0; k < CHUNK_E / 256; ++k) {
        int e = base + k * 256 + t;
        if (e < n_edges) atomicAdd(&hist[eidx[e] >> BUCKET_SHIFT], 1);
    }
    __syncthreads();
    for (int i = t; i < nb; i += 256) bh[i * nch + c] = hist[i];
}

// ---------------------------------------------------------------------------
// Scan kernels (generic exclusive prefix over n ints)
// ---------------------------------------------------------------------------
__global__ __launch_bounds__(256) void scan1_kernel(
    const int* __restrict__ in, int* __restrict__ out,
    int* __restrict__ partials, int n)
{
    __shared__ int s[256];
    const int b = blockIdx.x, t = threadIdx.x;
    const int base = b * SCAN_CHUNK + t * 8;
    int v[8]; int sum = 0;
    #pragma unroll
    for (int i = 0; i < 8; ++i) {
        v[i] = (base + i < n) ? in[base + i] : 0;
        sum += v[i];
    }
    s[t] = sum;
    __syncthreads();
    for (int off = 1; off < 256; off <<= 1) {
        int y = (t >= off) ? s[t - off] : 0;
        __syncthreads();
        s[t] += y;
        __syncthreads();
    }
    int excl = s[t] - sum;
    #pragma unroll
    for (int i = 0; i < 8; ++i) {
        if (base + i < n) out[base + i] = excl;
        excl += v[i];
    }
    if (t == 255) partials[b] = s[255];
}

__global__ __launch_bounds__(256) void scan2_kernel(int* partials, int nchunks)
{
    __shared__ int s[256];
    const int t = threadIdx.x;
    int v = (t < nchunks) ? partials[t] : 0;
    s[t] = v;
    __syncthreads();
    for (int off = 1; off < 256; off <<= 1) {
        int y = (t >= off) ? s[t - off] : 0;
        __syncthreads();
        s[t] += y;
        __syncthreads();
    }
    if (t < nchunks) partials[t] = s[t] - v;      // exclusive
}

__global__ __launch_bounds__(256) void scan3_kernel(
    int* __restrict__ data, const int* __restrict__ partials, int n)
{
    for (int i = blockIdx.x * blockDim.x + threadIdx.x; i < n;
         i += gridDim.x * blockDim.x)
        data[i] += partials[i / SCAN_CHUNK];
}

// ---------------------------------------------------------------------------
// Pass B: binned scatter into per-(bucket,chunk) contiguous runs.
// rec.x = (dstLocal << 20) | src,  rec.y = w bits.
// ---------------------------------------------------------------------------
__global__ __launch_bounds__(256) void binscatter_kernel(
    const int* __restrict__ eidx, const float* __restrict__ w,
    const int* __restrict__ scanned, int2* __restrict__ rec,
    int n_edges, int nb, int nch)
{
    __shared__ int cur[NB_MAX];
    const int c = blockIdx.x, t = threadIdx.x;
    for (int i = t; i < nb; i += 256) cur[i] = scanned[i * nch + c];
    __syncthreads();
    const int base = c * CHUNK_E;
    #pragma unroll 4
    for (int k = 0; k < CHUNK_E / 256; ++k) {
        int e = base + k * 256 + t;
        if (e < n_edges) {
            int dst = eidx[e];
            int src = eidx[n_edges + e];
            float wv = w[e];
            int b = dst >> BUCKET_SHIFT;
            int dl = dst & (BUCKET_NODES - 1);
            int pos = atomicAdd(&cur[b], 1);
            rec[pos] = make_int2((dl << 20) | src, __float_as_int(wv));
        }
    }
}

// ---------------------------------------------------------------------------
// Pass C: per-bucket aggregation, LATENCY-FIXED.
// 512 threads (8 waves) -> 16 waves/CU; 4 independent rec+h loads per wave
// per iteration (ILP=4) before the 4 ds_add_f32. acc[dl][0..63] is 256B
// contiguous -> 2-way bank aliasing = free.
// ---------------------------------------------------------------------------
__global__ __launch_bounds__(512, 4) void binagg_kernel(
    const int* __restrict__ scanned, const int2* __restrict__ rec,
    const float* __restrict__ h, float* __restrict__ agg,
    int n_edges, int nb, int nch, int n_nodes)
{
    __shared__ float acc[BUCKET_NODES][D_FEAT];   // 64 KB
    const int b = blockIdx.x, t = threadIdx.x;
    const int lane = t & 63, wid = t >> 6;        // 8 waves

    float* af = &acc[0][0];
    for (int i = t; i < BUCKET_NODES * D_FEAT; i += 512) af[i] = 0.f;
    __syncthreads();

    const int start = scanned[b * nch];
    const int end   = (b + 1 < nb) ? scanned[(b + 1) * nch] : n_edges;

    int i = start + wid * 4;
    for (; i + 3 < end; i += 8 * 4) {
        int2 r0 = rec[i];
        int2 r1 = rec[i + 1];
        int2 r2 = rec[i + 2];
        int2 r3 = rec[i + 3];
        float h0 = h[(size_t)(r0.x & 0xFFFFF) * D_FEAT + lane];
        float h1 = h[(size_t)(r1.x & 0xFFFFF) * D_FEAT + lane];
        float h2 = h[(size_t)(r2.x & 0xFFFFF) * D_FEAT + lane];
        float h3 = h[(size_t)(r3.x & 0xFFFFF) * D_FEAT + lane];
        unsafeAtomicAdd(&acc[r0.x >> 20][lane], __int_as_float(r0.y) * h0);
        unsafeAtomicAdd(&acc[r1.x >> 20][lane], __int_as_float(r1.y) * h1);
        unsafeAtomicAdd(&acc[r2.x >> 20][lane], __int_as_float(r2.y) * h2);
        unsafeAtomicAdd(&acc[r3.x >> 20][lane], __int_as_float(r3.y) * h3);
    }
    #pragma unroll
    for (int k = 0; k < 4; ++k) {
        if (i + k < end) {
            int2 r = rec[i + k];
            float hv = h[(size_t)(r.x & 0xFFFFF) * D_FEAT + lane];
            unsafeAtomicAdd(&acc[r.x >> 20][lane], __int_as_float(r.y) * hv);
        }
    }
    __syncthreads();

    const int node0 = b << BUCKET_SHIFT;
    for (int r = wid; r < BUCKET_NODES; r += 8) {
        int node = node0 + r;
        if (node < n_nodes)
            agg[(size_t)node * D_FEAT + lane] = acc[r][lane];
    }
}

// ---------------------------------------------------------------------------
// Fallback scatter (atomics) if workspace too small / shape unsupported
// ---------------------------------------------------------------------------
__global__ __launch_bounds__(256) void scatter_atomic_kernel(
    const int* __restrict__ eidx, const float* __restrict__ w,
    const float* __restrict__ h, float* __restrict__ agg, int n_edges)
{
    long long t = (long long)blockIdx.x * blockDim.x + threadIdx.x;
    int e = (int)(t >> 4);
    if (e >= n_edges) return;
    int c = ((int)t & 15) * 4;
    int dst = eidx[e];
    int src = eidx[n_edges + e];
    float wv = w[e];
    const float4 hv = *reinterpret_cast<const float4*>(h + (size_t)src * D_FEAT + c);
    float* p = agg + (size_t)dst * D_FEAT + c;
    unsafeAtomicAdd(p + 0, wv * hv.x);
    unsafeAtomicAdd(p + 1, wv * hv.y);
    unsafeAtomicAdd(p + 2, wv * hv.z);
    unsafeAtomicAdd(p + 3, wv * hv.w);
}

// ---------------------------------------------------------------------------
// GraphNorm, parallelized: partial reduce (G*NSPLIT blocks) -> finalize
// (G blocks) -> grid-stride apply.
// part layout: part[(g*NSPLIT + s)*128 + {0..63}=sum, {64..127}=sumsq]
// musc layout: musc[g*128 + j] = mu, musc[g*128 + 64 + j] = scale
// ---------------------------------------------------------------------------
__global__ __launch_bounds__(256) void norm_part_kernel(
    const float* __restrict__ io, float* __restrict__ part, int npg)
{
    const int g = blockIdx.x / NSPLIT;
    const int s = blockIdx.x % NSPLIT;
    const int t = threadIdx.x;
    const int j = t & 63;
    const int r = t >> 6;
    const int chunk = (npg + NSPLIT - 1) / NSPLIT;
    const int n0 = s * chunk;
    const int n1 = min(npg, n0 + chunk);
    const size_t base = (size_t)g * npg * D_FEAT;

    float sum = 0.f, sq = 0.f;
    for (int n = n0 + r; n < n1; n += 4) {
        float v = io[base + (size_t)n * D_FEAT + j];
        sum += v; sq += v * v;
    }
    __shared__ float s_red[2][4][64];
    s_red[0][r][j] = sum;
    s_red[1][r][j] = sq;
    __syncthreads();
    if (r == 0) {
        float S = s_red[0][0][j] + s_red[0][1][j] + s_red[0][2][j] + s_red[0][3][j];
        float Q = s_red[1][0][j] + s_red[1][1][j] + s_red[1][2][j] + s_red[1][3][j];
        part[(size_t)blockIdx.x * 128 + j]      = S;
        part[(size_t)blockIdx.x * 128 + 64 + j] = Q;
    }
}

__global__ __launch_bounds__(64) void norm_fin_kernel(
    const float* __restrict__ part, float* __restrict__ musc,
    const float* __restrict__ gamma, int npg)
{
    const int g = blockIdx.x;
    const int j = threadIdx.x;
    float S = 0.f, Q = 0.f;
    #pragma unroll
    for (int s = 0; s < NSPLIT; ++s) {
        S += part[(size_t)(g * NSPLIT + s) * 128 + j];
        Q += part[(size_t)(g * NSPLIT + s) * 128 + 64 + j];
    }
    float cnt = (float)npg;
    float mu = S / cnt;
    float var = (Q - cnt * mu * mu) / fmaxf(cnt - 1.f, 1.f);
    var = fmaxf(var, 0.f);
    musc[g * 128 + j]      = mu;
    musc[g * 128 + 64 + j] = gamma[j] / (sqrtf(var) + EPS_N);
}

__global__ __launch_bounds__(256) void norm_apply_kernel(
    float* __restrict__ io, const float* __restrict__ musc,
    const float* __restrict__ beta, int n_nodes, int npg)
{
    const int nf4 = n_nodes * 16;   // float4 count
    for (int i4 = blockIdx.x * blockDim.x + threadIdx.x; i4 < nf4;
         i4 += gridDim.x * blockDim.x) {
        int node = i4 >> 4;
        int j0 = (i4 & 15) * 4;
        int g = node / npg;
        float4 v  = *reinterpret_cast<float4*>(io + (size_t)i4 * 4);
        float4 mu = *reinterpret_cast<const float4*>(musc + g * 128 + j0);
        float4 sc = *reinterpret_cast<const float4*>(musc + g * 128 + 64 + j0);
        float4 be = *reinterpret_cast<const float4*>(beta + j0);
        v.x = (v.x - mu.x) * sc.x + be.x;
        v.y = (v.y - mu.y) * sc.y + be.y;
        v.z = (v.z - mu.z) * sc.z + be.z;
        v.w = (v.w - mu.w) * sc.w + be.w;
        *reinterpret_cast<float4*>(io + (size_t)i4 * 4) = v;
    }
}

extern "C" void kernel_launch(void* const* d_in, const int* in_sizes, int n_in,
                              void* d_out, int out_size, void* d_ws, size_t ws_size,
                              hipStream_t stream)
{
    const float* x      = (const float*)d_in[0];
    const float* states = (const float*)d_in[1];
    const int*   eidx   = (const int*)d_in[2];
    const float* w      = (const float*)d_in[3];
    const float* Ws     = (const float*)d_in[6];
    const float* W1     = (const float*)d_in[7];
    const float* W2     = (const float*)d_in[8];
    const float* gamma  = (const float*)d_in[9];
    const float* beta   = (const float*)d_in[10];

    const int n_nodes  = in_sizes[0] / D_FEAT;
    const int n_edges  = in_sizes[3];
    const int n_graphs = in_sizes[5];
    const int npg      = n_nodes / n_graphs;

    const int nb  = (n_nodes + BUCKET_NODES - 1) / BUCKET_NODES;  // 391
    const int nch = (n_edges + CHUNK_E - 1) / CHUNK_E;            // 293
    const int nscan = nb * nch;

    // workspace layout
    char* ws = (char*)d_ws;
    size_t hBytes   = (size_t)n_nodes * D_FEAT * sizeof(float);   // 25.6 MB
    size_t recBytes = (size_t)n_edges * sizeof(int2);             // 9.6 MB
    size_t bhBytes  = (size_t)nscan * sizeof(int);                // 458 KB
    size_t partBytes = 256 * sizeof(int);
    size_t need = hBytes + recBytes + bhBytes + partBytes;

    float* h   = (float*)ws;
    float* agg = (float*)d_out;

    // norm scratch aliases the rec region (rec is dead before norm runs)
    float* nrm_part = (float*)(ws + hBytes);
    float* nrm_musc = nrm_part + (size_t)n_graphs * NSPLIT * 128;

    mlp_kernel<<<(n_nodes + 63) / 64, 256, 0, stream>>>(x, states, Ws, W1, W2, h, n_nodes);

    const bool ok = (ws_size >= need) && (nb <= NB_MAX) && (n_nodes < (1 << 20));
    if (ok) {
        int2* rec      = (int2*)(ws + hBytes);
        int*  bh       = (int*)(ws + hBytes + recBytes);
        int*  partials = (int*)(ws + hBytes + recBytes + bhBytes);

        binhist_kernel<<<nch, 256, 0, stream>>>(eidx, bh, n_edges, nb, nch);

        int nchunks = (nscan + SCAN_CHUNK - 1) / SCAN_CHUNK;
        scan1_kernel<<<nchunks, 256, 0, stream>>>(bh, bh, partials, nscan);  // in-place
        scan2_kernel<<<1, 256, 0, stream>>>(partials, nchunks);
        scan3_kernel<<<256, 256, 0, stream>>>(bh, partials, nscan);

        binscatter_kernel<<<nch, 256, 0, stream>>>(eidx, w, bh, rec, n_edges, nb, nch);

        binagg_kernel<<<nb, 512, 0, stream>>>(bh, rec, h, agg, n_edges, nb, nch, n_nodes);
    } else {
        hipMemsetAsync(agg, 0, hBytes, stream);
        long long sthreads = (long long)n_edges * 16;
        int sblocks = (int)((sthreads + 255) / 256);
        scatter_atomic_kernel<<<sblocks, 256, 0, stream>>>(eidx, w, h, agg, n_edges);
    }

    norm_part_kernel<<<n_graphs * NSPLIT, 256, 0, stream>>>(agg, nrm_part, npg);
    norm_fin_kernel<<<n_graphs, 64, 0, stream>>>(nrm_part, nrm_musc, gamma, npg);
    norm_apply_kernel<<<1024, 256, 0, stream>>>(agg, nrm_musc, beta, n_nodes, npg);
}

// Round 9
// 178.424 us; speedup vs baseline: 3.9163x; 3.5148x over previous
//
#include <hip/hip_runtime.h>

#define D_FEAT 64
constexpr float SLOPE = 0.01f;
constexpr float EPS_N = 1e-6f;
constexpr int SCAN_CHUNK = 2048;   // elements per scan block (256 thr x 8)
constexpr int LDT = 66;            // LDS row stride (pad 64 -> 66)
constexpr int CHUNK_E = 4096;      // edges per binning block
constexpr int BUCKET_SHIFT = 8;    // 256 nodes per bucket
constexpr int BUCKET_NODES = 256;
constexpr int NB_MAX = 512;        // max buckets supported by LDS hist
constexpr int NSPLIT = 8;          // blocks per graph for norm partial reduce

__device__ __forceinline__ float lrelu(float v) { return v >= 0.f ? v : SLOPE * v; }

// ---------------------------------------------------------------------------
// Stage 1: h = (leaky_relu(leaky_relu(x + states@Ws^T) @ W1^T)) @ W2^T
// Register-tiled f32 GEMM: block = 64-node tile, thread = 4 nodes x 4 ch.
// ---------------------------------------------------------------------------
__global__ __launch_bounds__(256, 3) void mlp_kernel(
    const float* __restrict__ x, const float* __restrict__ states,
    const float* __restrict__ Ws, const float* __restrict__ W1,
    const float* __restrict__ W2, float* __restrict__ h, int n_nodes)
{
    __shared__ float S_t[D_FEAT * LDT];
    __shared__ float H_t[D_FEAT * LDT];
    __shared__ float W_t[D_FEAT * LDT];

    const int t  = threadIdx.x;
    const int tn = t & 15;          // node group (4 nodes)
    const int tc = t >> 4;          // channel group (4 ch)
    const int nb = blockIdx.x * 64; // tile base node

#define STAGE_W(Wp)                                                          \
    {                                                                        \
        const int wrow = t >> 2;                                             \
        _Pragma("unroll")                                                    \
        for (int s = (t & 3); s < 16; s += 4) {                              \
            float4 wv = *reinterpret_cast<const float4*>((Wp) + wrow * 64 + s * 4); \
            W_t[(s * 4 + 0) * LDT + wrow] = wv.x;                            \
            W_t[(s * 4 + 1) * LDT + wrow] = wv.y;                            \
            W_t[(s * 4 + 2) * LDT + wrow] = wv.z;                            \
            W_t[(s * 4 + 3) * LDT + wrow] = wv.w;                            \
        }                                                                    \
    }

    STAGE_W(Ws);
    {
        const int r = t >> 4, kg = t & 15;
        #pragma unroll
        for (int i = 0; i < 4; ++i) {
            int nloc = r + i * 16;
            int node = nb + nloc;
            float4 sv = make_float4(0.f, 0.f, 0.f, 0.f);
            if (node < n_nodes)
                sv = *reinterpret_cast<const float4*>(states + (size_t)node * D_FEAT + kg * 4);
            S_t[(kg * 4 + 0) * LDT + nloc] = sv.x;
            S_t[(kg * 4 + 1) * LDT + nloc] = sv.y;
            S_t[(kg * 4 + 2) * LDT + nloc] = sv.z;
            S_t[(kg * 4 + 3) * LDT + nloc] = sv.w;
        }
    }
    __syncthreads();

    float acc[4][4];

    // ---- stage 1: h2 = lrelu(x + states @ Ws^T) ----
    #pragma unroll
    for (int i = 0; i < 4; ++i) {
        int node = nb + tn * 4 + i;
        if (node < n_nodes) {
            float4 xv = *reinterpret_cast<const float4*>(x + (size_t)node * D_FEAT + tc * 4);
            acc[i][0] = xv.x; acc[i][1] = xv.y; acc[i][2] = xv.z; acc[i][3] = xv.w;
        } else {
            acc[i][0] = acc[i][1] = acc[i][2] = acc[i][3] = 0.f;
        }
    }
    #pragma unroll 8
    for (int k = 0; k < D_FEAT; ++k) {
        float4 a = *reinterpret_cast<const float4*>(&S_t[k * LDT + tn * 4]);
        float4 b = *reinterpret_cast<const float4*>(&W_t[k * LDT + tc * 4]);
        const float av[4] = {a.x, a.y, a.z, a.w};
        const float bv[4] = {b.x, b.y, b.z, b.w};
        #pragma unroll
        for (int i = 0; i < 4; ++i)
            #pragma unroll
            for (int j = 0; j < 4; ++j)
                acc[i][j] += av[i] * bv[j];
    }
    #pragma unroll
    for (int i = 0; i < 4; ++i)
        #pragma unroll
        for (int j = 0; j < 4; ++j)
            H_t[(tc * 4 + j) * LDT + tn * 4 + i] = lrelu(acc[i][j]);
    __syncthreads();

    STAGE_W(W1);
    __syncthreads();

    // ---- stage 2: h3 = lrelu(h2 @ W1^T) ----
    #pragma unroll
    for (int i = 0; i < 4; ++i)
        #pragma unroll
        for (int j = 0; j < 4; ++j)
            acc[i][j] = 0.f;
    #pragma unroll 8
    for (int k = 0; k < D_FEAT; ++k) {
        float4 a = *reinterpret_cast<const float4*>(&H_t[k * LDT + tn * 4]);
        float4 b = *reinterpret_cast<const float4*>(&W_t[k * LDT + tc * 4]);
        const float av[4] = {a.x, a.y, a.z, a.w};
        const float bv[4] = {b.x, b.y, b.z, b.w};
        #pragma unroll
        for (int i = 0; i < 4; ++i)
            #pragma unroll
            for (int j = 0; j < 4; ++j)
                acc[i][j] += av[i] * bv[j];
    }
    #pragma unroll
    for (int i = 0; i < 4; ++i)
        #pragma unroll
        for (int j = 0; j < 4; ++j)
            S_t[(tc * 4 + j) * LDT + tn * 4 + i] = lrelu(acc[i][j]);
    __syncthreads();

    STAGE_W(W2);
    __syncthreads();

    // ---- stage 3: h = h3 @ W2^T ----
    #pragma unroll
    for (int i = 0; i < 4; ++i)
        #pragma unroll
        for (int j = 0; j < 4; ++j)
            acc[i][j] = 0.f;
    #pragma unroll 8
    for (int k = 0; k < D_FEAT; ++k) {
        float4 a = *reinterpret_cast<const float4*>(&S_t[k * LDT + tn * 4]);
        float4 b = *reinterpret_cast<const float4*>(&W_t[k * LDT + tc * 4]);
        const float av[4] = {a.x, a.y, a.z, a.w};
        const float bv[4] = {b.x, b.y, b.z, b.w};
        #pragma unroll
        for (int i = 0; i < 4; ++i)
            #pragma unroll
            for (int j = 0; j < 4; ++j)
                acc[i][j] += av[i] * bv[j];
    }
    #pragma unroll
    for (int i = 0; i < 4; ++i) {
        int node = nb + tn * 4 + i;
        if (node < n_nodes) {
            float4 o = make_float4(acc[i][0], acc[i][1], acc[i][2], acc[i][3]);
            *reinterpret_cast<float4*>(h + (size_t)node * D_FEAT + tc * 4) = o;
        }
    }
#undef STAGE_W
}

// ---------------------------------------------------------------------------
// Pass A: per-chunk bucket histogram (bucket = dst >> BUCKET_SHIFT).
// ---------------------------------------------------------------------------
__global__ __launch_bounds__(256) void binhist_kernel(
    const int* __restrict__ eidx, int* __restrict__ bh,
    int n_edges, int nb, int nch)
{
    __shared__ int hist[NB_MAX];
    const int c = blockIdx.x, t = threadIdx.x;
    for (int i = t; i < nb; i += 256) hist[i] = 0;
    __syncthreads();
    const int base = c * CHUNK_E;
    #pragma unroll 4
    for (int k = 0; k < CHUNK_E / 256; ++k) {
        int e = base + k * 256 + t;
        if (e < n_edges) atomicAdd(&hist[eidx[e] >> BUCKET_SHIFT], 1);
    }
    __syncthreads();
    for (int i = t; i < nb; i += 256) bh[i * nch + c] = hist[i];
}

// ---------------------------------------------------------------------------
// Scan kernels (generic exclusive prefix over n ints)
// ---------------------------------------------------------------------------
__global__ __launch_bounds__(256) void scan1_kernel(
    const int* __restrict__ in, int* __restrict__ out,
    int* __restrict__ partials, int n)
{
    __shared__ int s[256];
    const int b = blockIdx.x, t = threadIdx.x;
    const int base = b * SCAN_CHUNK + t * 8;
    int v[8]; int sum = 0;
    #pragma unroll
    for (int i = 0; i < 8; ++i) {
        v[i] = (base + i < n) ? in[base + i] : 0;
        sum += v[i];
    }
    s[t] = sum;
    __syncthreads();
    for (int off = 1; off < 256; off <<= 1) {
        int y = (t >= off) ? s[t - off] : 0;
        __syncthreads();
        s[t] += y;
        __syncthreads();
    }
    int excl = s[t] - sum;
    #pragma unroll
    for (int i = 0; i < 8; ++i) {
        if (base + i < n) out[base + i] = excl;
        excl += v[i];
    }
    if (t == 255) partials[b] = s[255];
}

__global__ __launch_bounds__(256) void scan2_kernel(int* partials, int nchunks)
{
    __shared__ int s[256];
    const int t = threadIdx.x;
    int v = (t < nchunks) ? partials[t] : 0;
    s[t] = v;
    __syncthreads();
    for (int off = 1; off < 256; off <<= 1) {
        int y = (t >= off) ? s[t - off] : 0;
        __syncthreads();
        s[t] += y;
        __syncthreads();
    }
    if (t < nchunks) partials[t] = s[t] - v;      // exclusive
}

__global__ __launch_bounds__(256) void scan3_kernel(
    int* __restrict__ data, const int* __restrict__ partials, int n)
{
    for (int i = blockIdx.x * blockDim.x + threadIdx.x; i < n;
         i += gridDim.x * blockDim.x)
        data[i] += partials[i / SCAN_CHUNK];
}

// ---------------------------------------------------------------------------
// Pass B: binned scatter into per-(bucket,chunk) contiguous runs.
// rec.x = (dstLocal << 20) | src,  rec.y = w bits.
// ---------------------------------------------------------------------------
__global__ __launch_bounds__(256) void binscatter_kernel(
    const int* __restrict__ eidx, const float* __restrict__ w,
    const int* __restrict__ scanned, int2* __restrict__ rec,
    int n_edges, int nb, int nch)
{
    __shared__ int cur[NB_MAX];
    const int c = blockIdx.x, t = threadIdx.x;
    for (int i = t; i < nb; i += 256) cur[i] = scanned[i * nch + c];
    __syncthreads();
    const int base = c * CHUNK_E;
    #pragma unroll 4
    for (int k = 0; k < CHUNK_E / 256; ++k) {
        int e = base + k * 256 + t;
        if (e < n_edges) {
            int dst = eidx[e];
            int src = eidx[n_edges + e];
            float wv = w[e];
            int b = dst >> BUCKET_SHIFT;
            int dl = dst & (BUCKET_NODES - 1);
            int pos = atomicAdd(&cur[b], 1);
            rec[pos] = make_int2((dl << 20) | src, __float_as_int(wv));
        }
    }
}

// ---------------------------------------------------------------------------
// Pass B2: per-bucket counting sort into per-NODE order + row_start build.
// Block b owns bucket b (run [S,E) of rec). LDS int counts + scan; writes
// rec2 in node order and row_start[node]. All traffic bucket-local.
// ---------------------------------------------------------------------------
__global__ __launch_bounds__(256) void bucket_sort_kernel(
    const int* __restrict__ scanned, const int2* __restrict__ rec,
    int2* __restrict__ rec2, int* __restrict__ row_start,
    int n_edges, int nb, int nch, int n_nodes)
{
    __shared__ int cnt[BUCKET_NODES];
    __shared__ int s[BUCKET_NODES];
    __shared__ int pos[BUCKET_NODES];

    const int b = blockIdx.x, t = threadIdx.x;
    const int S = scanned[b * nch];
    const int E = (b + 1 < nb) ? scanned[(b + 1) * nch] : n_edges;

    cnt[t] = 0;
    __syncthreads();
    for (int i = S + t; i < E; i += 256)
        atomicAdd(&cnt[rec[i].x >> 20], 1);
    __syncthreads();

    // exclusive scan of cnt
    int my = cnt[t];
    s[t] = my;
    __syncthreads();
    for (int off = 1; off < 256; off <<= 1) {
        int y = (t >= off) ? s[t - off] : 0;
        __syncthreads();
        s[t] += y;
        __syncthreads();
    }
    int excl = s[t] - my;
    pos[t] = S + excl;
    const int node = (b << BUCKET_SHIFT) + t;
    if (node < n_nodes) row_start[node] = S + excl;
    if (b == nb - 1 && t == 0) row_start[n_nodes] = n_edges;
    __syncthreads();

    for (int i = S + t; i < E; i += 256) {
        int2 r = rec[i];
        int p = atomicAdd(&pos[r.x >> 20], 1);
        rec2[p] = r;
    }
}

// ---------------------------------------------------------------------------
// Pass C: atomic-free gather. One wave per destination node, lane = channel.
// 4 independent accumulator chains + ILP-4 loads; VGPR-capped for 32 waves/CU.
// ---------------------------------------------------------------------------
__global__ __launch_bounds__(256, 8) void node_gather_kernel(
    const int* __restrict__ row_start, const int2* __restrict__ rec2,
    const float* __restrict__ h, float* __restrict__ agg, int n_nodes)
{
    const int node = blockIdx.x * 4 + (threadIdx.x >> 6);
    const int lane = threadIdx.x & 63;
    if (node >= n_nodes) return;

    const int start = row_start[node];
    const int end   = row_start[node + 1];

    float a0 = 0.f, a1 = 0.f, a2 = 0.f, a3 = 0.f;
    int i = start;
    for (; i + 4 <= end; i += 4) {
        int2 r0 = rec2[i];
        int2 r1 = rec2[i + 1];
        int2 r2 = rec2[i + 2];
        int2 r3 = rec2[i + 3];
        float h0 = h[(size_t)(r0.x & 0xFFFFF) * D_FEAT + lane];
        float h1 = h[(size_t)(r1.x & 0xFFFFF) * D_FEAT + lane];
        float h2 = h[(size_t)(r2.x & 0xFFFFF) * D_FEAT + lane];
        float h3 = h[(size_t)(r3.x & 0xFFFFF) * D_FEAT + lane];
        a0 += __int_as_float(r0.y) * h0;
        a1 += __int_as_float(r1.y) * h1;
        a2 += __int_as_float(r2.y) * h2;
        a3 += __int_as_float(r3.y) * h3;
    }
    for (; i < end; ++i) {
        int2 r = rec2[i];
        a0 += __int_as_float(r.y) * h[(size_t)(r.x & 0xFFFFF) * D_FEAT + lane];
    }
    agg[(size_t)node * D_FEAT + lane] = (a0 + a1) + (a2 + a3);
}

// ---------------------------------------------------------------------------
// Fallback scatter (atomics) if workspace too small / shape unsupported
// ---------------------------------------------------------------------------
__global__ __launch_bounds__(256) void scatter_atomic_kernel(
    const int* __restrict__ eidx, const float* __restrict__ w,
    const float* __restrict__ h, float* __restrict__ agg, int n_edges)
{
    long long t = (long long)blockIdx.x * blockDim.x + threadIdx.x;
    int e = (int)(t >> 4);
    if (e >= n_edges) return;
    int c = ((int)t & 15) * 4;
    int dst = eidx[e];
    int src = eidx[n_edges + e];
    float wv = w[e];
    const float4 hv = *reinterpret_cast<const float4*>(h + (size_t)src * D_FEAT + c);
    float* p = agg + (size_t)dst * D_FEAT + c;
    unsafeAtomicAdd(p + 0, wv * hv.x);
    unsafeAtomicAdd(p + 1, wv * hv.y);
    unsafeAtomicAdd(p + 2, wv * hv.z);
    unsafeAtomicAdd(p + 3, wv * hv.w);
}

// ---------------------------------------------------------------------------
// GraphNorm, parallelized: partial reduce -> finalize -> apply.
// ---------------------------------------------------------------------------
__global__ __launch_bounds__(256) void norm_part_kernel(
    const float* __restrict__ io, float* __restrict__ part, int npg)
{
    const int g = blockIdx.x / NSPLIT;
    const int s = blockIdx.x % NSPLIT;
    const int t = threadIdx.x;
    const int j = t & 63;
    const int r = t >> 6;
    const int chunk = (npg + NSPLIT - 1) / NSPLIT;
    const int n0 = s * chunk;
    const int n1 = min(npg, n0 + chunk);
    const size_t base = (size_t)g * npg * D_FEAT;

    float sum = 0.f, sq = 0.f;
    for (int n = n0 + r; n < n1; n += 4) {
        float v = io[base + (size_t)n * D_FEAT + j];
        sum += v; sq += v * v;
    }
    __shared__ float s_red[2][4][64];
    s_red[0][r][j] = sum;
    s_red[1][r][j] = sq;
    __syncthreads();
    if (r == 0) {
        float S = s_red[0][0][j] + s_red[0][1][j] + s_red[0][2][j] + s_red[0][3][j];
        float Q = s_red[1][0][j] + s_red[1][1][j] + s_red[1][2][j] + s_red[1][3][j];
        part[(size_t)blockIdx.x * 128 + j]      = S;
        part[(size_t)blockIdx.x * 128 + 64 + j] = Q;
    }
}

__global__ __launch_bounds__(64) void norm_fin_kernel(
    const float* __restrict__ part, float* __restrict__ musc,
    const float* __restrict__ gamma, int npg)
{
    const int g = blockIdx.x;
    const int j = threadIdx.x;
    float S = 0.f, Q = 0.f;
    #pragma unroll
    for (int s = 0; s < NSPLIT; ++s) {
        S += part[(size_t)(g * NSPLIT + s) * 128 + j];
        Q += part[(size_t)(g * NSPLIT + s) * 128 + 64 + j];
    }
    float cnt = (float)npg;
    float mu = S / cnt;
    float var = (Q - cnt * mu * mu) / fmaxf(cnt - 1.f, 1.f);
    var = fmaxf(var, 0.f);
    musc[g * 128 + j]      = mu;
    musc[g * 128 + 64 + j] = gamma[j] / (sqrtf(var) + EPS_N);
}

__global__ __launch_bounds__(256) void norm_apply_kernel(
    float* __restrict__ io, const float* __restrict__ musc,
    const float* __restrict__ beta, int n_nodes, int npg)
{
    const int nf4 = n_nodes * 16;   // float4 count
    for (int i4 = blockIdx.x * blockDim.x + threadIdx.x; i4 < nf4;
         i4 += gridDim.x * blockDim.x) {
        int node = i4 >> 4;
        int j0 = (i4 & 15) * 4;
        int g = node / npg;
        float4 v  = *reinterpret_cast<float4*>(io + (size_t)i4 * 4);
        float4 mu = *reinterpret_cast<const float4*>(musc + g * 128 + j0);
        float4 sc = *reinterpret_cast<const float4*>(musc + g * 128 + 64 + j0);
        float4 be = *reinterpret_cast<const float4*>(beta + j0);
        v.x = (v.x - mu.x) * sc.x + be.x;
        v.y = (v.y - mu.y) * sc.y + be.y;
        v.z = (v.z - mu.z) * sc.z + be.z;
        v.w = (v.w - mu.w) * sc.w + be.w;
        *reinterpret_cast<float4*>(io + (size_t)i4 * 4) = v;
    }
}

extern "C" void kernel_launch(void* const* d_in, const int* in_sizes, int n_in,
                              void* d_out, int out_size, void* d_ws, size_t ws_size,
                              hipStream_t stream)
{
    const float* x      = (const float*)d_in[0];
    const float* states = (const float*)d_in[1];
    const int*   eidx   = (const int*)d_in[2];
    const float* w      = (const float*)d_in[3];
    const float* Ws     = (const float*)d_in[6];
    const float* W1     = (const float*)d_in[7];
    const float* W2     = (const float*)d_in[8];
    const float* gamma  = (const float*)d_in[9];
    const float* beta   = (const float*)d_in[10];

    const int n_nodes  = in_sizes[0] / D_FEAT;
    const int n_edges  = in_sizes[3];
    const int n_graphs = in_sizes[5];
    const int npg      = n_nodes / n_graphs;

    const int nb  = (n_nodes + BUCKET_NODES - 1) / BUCKET_NODES;  // 391
    const int nch = (n_edges + CHUNK_E - 1) / CHUNK_E;            // 293
    const int nscan = nb * nch;

    // workspace layout: h | rec | rec2 | bh | partials | row_start
    char* ws = (char*)d_ws;
    size_t hBytes    = (size_t)n_nodes * D_FEAT * sizeof(float);  // 25.6 MB
    size_t recBytes  = (size_t)n_edges * sizeof(int2);            // 9.6 MB
    size_t bhBytes   = (size_t)nscan * sizeof(int);               // 458 KB
    size_t partBytes = 256 * sizeof(int);
    size_t rsBytes   = (size_t)(n_nodes + 1) * sizeof(int);
    size_t need = hBytes + 2 * recBytes + bhBytes + partBytes + rsBytes;

    float* h   = (float*)ws;
    float* agg = (float*)d_out;

    // norm scratch aliases the rec region (rec is dead before norm runs)
    float* nrm_part = (float*)(ws + hBytes);
    float* nrm_musc = nrm_part + (size_t)n_graphs * NSPLIT * 128;

    mlp_kernel<<<(n_nodes + 63) / 64, 256, 0, stream>>>(x, states, Ws, W1, W2, h, n_nodes);

    const bool ok = (ws_size >= need) && (nb <= NB_MAX) && (n_nodes < (1 << 20));
    if (ok) {
        int2* rec      = (int2*)(ws + hBytes);
        int2* rec2     = (int2*)(ws + hBytes + recBytes);
        int*  bh       = (int*)(ws + hBytes + 2 * recBytes);
        int*  partials = (int*)(ws + hBytes + 2 * recBytes + bhBytes);
        int*  row_start= (int*)(ws + hBytes + 2 * recBytes + bhBytes + partBytes);

        binhist_kernel<<<nch, 256, 0, stream>>>(eidx, bh, n_edges, nb, nch);

        int nchunks = (nscan + SCAN_CHUNK - 1) / SCAN_CHUNK;
        scan1_kernel<<<nchunks, 256, 0, stream>>>(bh, bh, partials, nscan);  // in-place
        scan2_kernel<<<1, 256, 0, stream>>>(partials, nchunks);
        scan3_kernel<<<256, 256, 0, stream>>>(bh, partials, nscan);

        binscatter_kernel<<<nch, 256, 0, stream>>>(eidx, w, bh, rec, n_edges, nb, nch);

        bucket_sort_kernel<<<nb, 256, 0, stream>>>(bh, rec, rec2, row_start,
                                                   n_edges, nb, nch, n_nodes);

        node_gather_kernel<<<(n_nodes + 3) / 4, 256, 0, stream>>>(row_start, rec2, h,
                                                                  agg, n_nodes);
    } else {
        hipMemsetAsync(agg, 0, hBytes, stream);
        long long sthreads = (long long)n_edges * 16;
        int sblocks = (int)((sthreads + 255) / 256);
        scatter_atomic_kernel<<<sblocks, 256, 0, stream>>>(eidx, w, h, agg, n_edges);
    }

    norm_part_kernel<<<n_graphs * NSPLIT, 256, 0, stream>>>(agg, nrm_part, npg);
    norm_fin_kernel<<<n_graphs, 64, 0, stream>>>(nrm_part, nrm_musc, gamma, npg);
    norm_apply_kernel<<<1024, 256, 0, stream>>>(agg, nrm_musc, beta, n_nodes, npg);
}